// Round 3
// baseline (229.298 us; speedup 1.0000x reference)
//
#include <hip/hip_runtime.h>
#include <hip/hip_bf16.h>
#include <math.h>

#define TT 3
#define HH 96
#define WWD 96
#define CCH 128
#define NROWS (TT*HH*WWD)   // 27648

typedef __attribute__((ext_vector_type(8))) short short8;
typedef __attribute__((ext_vector_type(4))) float float4v;

__device__ __forceinline__ float bf_lo(unsigned u){ union{unsigned u;float f;}c; c.u=u<<16; return c.f; }
__device__ __forceinline__ float bf_hi(unsigned u){ union{unsigned u;float f;}c; c.u=u&0xffff0000u; return c.f; }
__device__ __forceinline__ unsigned short f2bf(float f){ __hip_bfloat16 h=__float2bfloat16(f); return *(unsigned short*)&h; }

// ---------------- Kernel 0: transpose Wq/Wk/Wv into bf16 K-contiguous [384][128] ----------------
__global__ void prep_kernel(const float* __restrict__ Wq, const float* __restrict__ Wk,
                            const float* __restrict__ Wv, __hip_bfloat16* __restrict__ Wt) {
    const float* src = (blockIdx.x == 0) ? Wq : (blockIdx.x == 1) ? Wk : Wv;
    __hip_bfloat16* dst = Wt + blockIdx.x * 128 * 128;
    for (int e = threadIdx.x; e < 16384; e += 256) {
        int k = e >> 7, n = e & 127;
        dst[n * 128 + k] = __float2bfloat16(src[e]);
    }
}

// ---------------- Kernel 1: QKV projection, bf16 MFMA ----------------
// Block 256 thr = 4 waves; M-tile 32 rows; wave w covers concat cols [w*96, w*96+96).
// Outputs: Q,K bf16 (emb added), V fp32.
__launch_bounds__(256)
__global__ void qkv_kernel(const float* __restrict__ x,
                           const __hip_bfloat16* __restrict__ Wt,
                           const float* __restrict__ temp_emb,
                           const float* __restrict__ sp_emb,
                           __hip_bfloat16* __restrict__ Qb,
                           __hip_bfloat16* __restrict__ Kb,
                           float* __restrict__ Vb) {
    __shared__ unsigned short xs[32 * 136];
    const int tid = threadIdx.x;
    const int m0 = blockIdx.x * 32;

    // stage x rows -> bf16 LDS (stride 136)
    for (int c = tid; c < 1024; c += 256) {
        int row = c >> 5, col = (c & 31) * 4;
        float4 v = *(const float4*)(x + (size_t)(m0 + row) * CCH + col);
        ushort4 u;
        u.x = f2bf(v.x); u.y = f2bf(v.y); u.z = f2bf(v.z); u.w = f2bf(v.w);
        *(ushort4*)&xs[row * 136 + col] = u;
    }
    __syncthreads();

    const int w = tid >> 6, l = tid & 63, quad = l >> 4, l16 = l & 15;
    const int n0 = w * 96;
    float4v acc[2][6];
#pragma unroll
    for (int r = 0; r < 2; ++r)
#pragma unroll
        for (int c = 0; c < 6; ++c) acc[r][c] = (float4v){0.f, 0.f, 0.f, 0.f};

#pragma unroll
    for (int ks = 0; ks < 4; ++ks) {
        short8 a0 = *(const short8*)&xs[l16 * 136 + ks * 32 + quad * 8];
        short8 a1 = *(const short8*)&xs[(16 + l16) * 136 + ks * 32 + quad * 8];
#pragma unroll
        for (int c = 0; c < 6; ++c) {
            short8 b = *(const short8*)((const unsigned short*)Wt
                        + (size_t)(n0 + c * 16 + l16) * CCH + ks * 32 + quad * 8);
            acc[0][c] = __builtin_amdgcn_mfma_f32_16x16x32_bf16(a0, b, acc[0][c], 0, 0, 0);
            acc[1][c] = __builtin_amdgcn_mfma_f32_16x16x32_bf16(a1, b, acc[1][c], 0, 0, 0);
        }
    }

#pragma unroll
    for (int r = 0; r < 2; ++r) {
#pragma unroll
        for (int c = 0; c < 6; ++c) {
            int col_cat = n0 + c * 16 + l16;
            int mat = col_cat >> 7, col = col_cat & 127;
#pragma unroll
            for (int reg = 0; reg < 4; ++reg) {
                int row = m0 + r * 16 + quad * 4 + reg;
                float v = acc[r][c][reg];
                int t = row / (HH * WWD);
                int rem = row - t * (HH * WWD);
                if (mat == 0) {
                    int yy = rem / WWD, xx = rem - (rem / WWD) * WWD;
                    int qidx = (yy - min(max(yy, 2), 93) + 2) * 5 + (xx - min(max(xx, 2), 93) + 2);
                    v += temp_emb[t * CCH + col] + sp_emb[qidx * CCH + col];
                    Qb[(size_t)row * CCH + col] = __float2bfloat16(v);
                } else if (mat == 1) {
                    v += temp_emb[t * CCH + col];
                    Kb[(size_t)row * CCH + col] = __float2bfloat16(v);
                } else {
                    Vb[(size_t)row * CCH + col] = v;
                }
            }
        }
    }
}

// ---------------- Kernel 2: local attention, d-split threads, bf16 K / fp32 V in LDS ----------------
#define ATX 2
#define ATY 4
#define AHX 6
#define AHY 8
#define KSTR 136
#define VSTR 132

__launch_bounds__(384)
__global__ void attn_kernel(const __hip_bfloat16* Qb,
                            const __hip_bfloat16* __restrict__ Kb,
                            const float* __restrict__ Vb,
                            const float* __restrict__ sp_emb,
                            __hip_bfloat16* Ab) {
    __shared__ unsigned short Ks[AHY * AHX * KSTR];   // 13.1 KB
    __shared__ float Vs[AHY * AHX * VSTR];            // 25.3 KB

    const int tid = threadIdx.x;
    const int ds = tid & 1, h = (tid >> 1) & 7, qxl = (tid >> 4) & 1, qyl = (tid >> 5) & 3, tq = tid >> 7;
    const int bx = blockIdx.x % (WWD / ATX), by = blockIdx.x / (WWD / ATX);
    const int x0 = bx * ATX, y0 = by * ATY;
    const int xlo = min(min(max(x0, 2), 93) - 2, WWD - AHX);
    const int ylo = min(min(max(y0, 2), 93) - 2, HH - AHY);
    const int yy = y0 + qyl, xx = x0 + qxl;
    const int yc = min(max(yy, 2), 93), xc = min(max(xx, 2), 93);
    const int lyo = yc - 2 - ylo, lxo = xc - 2 - xlo;
    const int hd = h * 16 + ds * 8;
    const int qrow = tq * (HH * WWD) + yy * WWD + xx;

    // Q (bf16) -> 8 fp32, pre-scaled
    float qv[8];
    {
        uint4 q = *(const uint4*)((const unsigned short*)Qb + (size_t)qrow * CCH + hd);
        qv[0] = bf_lo(q.x) * 0.25f; qv[1] = bf_hi(q.x) * 0.25f;
        qv[2] = bf_lo(q.y) * 0.25f; qv[3] = bf_hi(q.y) * 0.25f;
        qv[4] = bf_lo(q.z) * 0.25f; qv[5] = bf_hi(q.z) * 0.25f;
        qv[6] = bf_lo(q.w) * 0.25f; qv[7] = bf_hi(q.w) * 0.25f;
    }

    // qsp[p] = (scaled q) . sp_emb[p]  (full over both d-halves via shfl)
    float qsp[25];
#pragma unroll
    for (int p = 0; p < 25; ++p) {
        const float* spp = sp_emb + p * CCH + hd;
        float4 s0 = *(const float4*)spp, s1 = *(const float4*)(spp + 4);
        qsp[p] = qv[0] * s0.x + qv[1] * s0.y + qv[2] * s0.z + qv[3] * s0.w
               + qv[4] * s1.x + qv[5] * s1.y + qv[6] * s1.z + qv[7] * s1.w;
    }
#pragma unroll
    for (int p = 0; p < 25; ++p) qsp[p] += __shfl_xor(qsp[p], 1);

    float m = -1e30f, l = 0.f;
    float acc[8];
#pragma unroll
    for (int d = 0; d < 8; ++d) acc[d] = 0.f;

    for (int t = 0; t < TT; ++t) {
        __syncthreads();
        // stage K halo (bf16) 48 rows x 128
        for (int e = tid; e < AHY * AHX * 16; e += 384) {
            int r = e >> 4, ch = e & 15;
            int gy = ylo + r / AHX, gx = xlo + r % AHX;
            size_t g = ((size_t)(t * HH + gy) * WWD + gx) * CCH + ch * 8;
            *(uint4*)&Ks[r * KSTR + ch * 8] = *(const uint4*)((const unsigned short*)Kb + g);
        }
        // stage V halo (fp32)
        for (int e = tid; e < AHY * AHX * 32; e += 384) {
            int r = e >> 5, ch = e & 31;
            int gy = ylo + r / AHX, gx = xlo + r % AHX;
            size_t g = ((size_t)(t * HH + gy) * WWD + gx) * CCH + ch * 4;
            *(float4*)&Vs[r * VSTR + ch * 4] = *(const float4*)(Vb + g);
        }
        __syncthreads();

        float s[25];
#pragma unroll
        for (int py = 0; py < 5; ++py) {
            int rb = (lyo + py) * AHX + lxo;
#pragma unroll
            for (int px = 0; px < 5; ++px) {
                uint4 k = *(const uint4*)&Ks[(rb + px) * KSTR + hd];
                s[py * 5 + px] =
                    qv[0] * bf_lo(k.x) + qv[1] * bf_hi(k.x) + qv[2] * bf_lo(k.y) + qv[3] * bf_hi(k.y)
                  + qv[4] * bf_lo(k.z) + qv[5] * bf_hi(k.z) + qv[6] * bf_lo(k.w) + qv[7] * bf_hi(k.w);
            }
        }
#pragma unroll
        for (int p = 0; p < 25; ++p) s[p] = s[p] + __shfl_xor(s[p], 1) + qsp[p];

        float fm = m;
#pragma unroll
        for (int p = 0; p < 25; ++p) fm = fmaxf(fm, s[p]);
        float corr = __expf(m - fm);
        m = fm; l *= corr;
#pragma unroll
        for (int d = 0; d < 8; ++d) acc[d] *= corr;
#pragma unroll
        for (int py = 0; py < 5; ++py) {
            int rb = (lyo + py) * AHX + lxo;
#pragma unroll
            for (int px = 0; px < 5; ++px) {
                float w = __expf(s[py * 5 + px] - fm);
                l += w;
                const float* vp = &Vs[(rb + px) * VSTR + hd];
                float4 v0 = *(const float4*)vp, v1 = *(const float4*)(vp + 4);
                acc[0] += w * v0.x; acc[1] += w * v0.y; acc[2] += w * v0.z; acc[3] += w * v0.w;
                acc[4] += w * v1.x; acc[5] += w * v1.y; acc[6] += w * v1.z; acc[7] += w * v1.w;
            }
        }
    }

    float inv = 1.f / l;
    uint4 ov;
    ov.x = (unsigned)f2bf(acc[0] * inv) | ((unsigned)f2bf(acc[1] * inv) << 16);
    ov.y = (unsigned)f2bf(acc[2] * inv) | ((unsigned)f2bf(acc[3] * inv) << 16);
    ov.z = (unsigned)f2bf(acc[4] * inv) | ((unsigned)f2bf(acc[5] * inv) << 16);
    ov.w = (unsigned)f2bf(acc[6] * inv) | ((unsigned)f2bf(acc[7] * inv) << 16);
    *(uint4*)((unsigned short*)Ab + (size_t)qrow * CCH + hd) = ov;
}

// ---------------- Kernel 3: output projection (fp32 compute, bf16 A input) + transpose scatter ----------------
__launch_bounds__(256)
__global__ void out_proj_kernel(const __hip_bfloat16* __restrict__ A,
                                const float* __restrict__ Wo,
                                float* __restrict__ out) {
    __shared__ __align__(16) float xs[32][132];
    __shared__ __align__(16) float ws[64][132];
    const int tid = threadIdx.x;
    const int tx = tid & 31;
    const int ty = tid >> 5;
    const int r0 = blockIdx.x * 32;

    for (int e = tid; e < 512; e += 256) {
        int row = e >> 4, ch = e & 15;
        uint4 a = *(const uint4*)((const unsigned short*)A + (size_t)(r0 + row) * CCH + ch * 8);
        float4 f0 = {bf_lo(a.x), bf_hi(a.x), bf_lo(a.y), bf_hi(a.y)};
        float4 f1 = {bf_lo(a.z), bf_hi(a.z), bf_lo(a.w), bf_hi(a.w)};
        *(float4*)&xs[row][ch * 8] = f0;
        *(float4*)&xs[row][ch * 8 + 4] = f1;
    }

    float acc[4][4];
#pragma unroll
    for (int i = 0; i < 4; ++i)
#pragma unroll
        for (int j = 0; j < 4; ++j) acc[i][j] = 0.f;

    for (int c0 = 0; c0 < 128; c0 += 64) {
        __syncthreads();
        const float4* wsrc = (const float4*)(Wo + (size_t)c0 * CCH);
        for (int e = tid; e < 64 * 128 / 4; e += 256) {
            float4 v4 = wsrc[e];
            int r = (e * 4) >> 7;
            int c = (e * 4) & 127;
            *(float4*)&ws[r][c] = v4;
        }
        __syncthreads();
#pragma unroll 8
        for (int cc = 0; cc < 64; ++cc) {
            float4 w4 = *(const float4*)&ws[cc][tx * 4];
#pragma unroll
            for (int i = 0; i < 4; ++i) {
                float xv = xs[ty * 4 + i][c0 + cc];
                acc[i][0] += xv * w4.x;
                acc[i][1] += xv * w4.y;
                acc[i][2] += xv * w4.z;
                acc[i][3] += xv * w4.w;
            }
        }
    }
#pragma unroll
    for (int i = 0; i < 4; ++i) {
        int row = r0 + ty * 4 + i;
        int t = row / (HH * WWD);
        int rem = row - t * (HH * WWD);
        int yy = rem / WWD;
        int xx = rem - yy * WWD;
        int k0 = tx * 4;
        float4 o;
        o.x = acc[i][0]; o.y = acc[i][1]; o.z = acc[i][2]; o.w = acc[i][3];
        size_t oidx = ((size_t)(yy * WWD + xx) * TT + t) * CCH + k0;
        *(float4*)&out[oidx] = o;
    }
}

extern "C" void kernel_launch(void* const* d_in, const int* in_sizes, int n_in,
                              void* d_out, int out_size, void* d_ws, size_t ws_size,
                              hipStream_t stream) {
    const float* x        = (const float*)d_in[0];
    const float* Wq       = (const float*)d_in[1];
    const float* Wk       = (const float*)d_in[2];
    const float* Wv       = (const float*)d_in[3];
    const float* Wo       = (const float*)d_in[4];
    const float* temp_emb = (const float*)d_in[5];
    const float* sp_emb   = (const float*)d_in[6];
    float* out = (float*)d_out;

    float* Vb = (float*)d_ws;                                     // NROWS*128 fp32
    __hip_bfloat16* Qb = (__hip_bfloat16*)((char*)d_ws + (size_t)NROWS * CCH * 4);
    __hip_bfloat16* Kb = Qb + (size_t)NROWS * CCH;
    __hip_bfloat16* Wt = Kb + (size_t)NROWS * CCH;                // 384*128 bf16

    prep_kernel<<<3, 256, 0, stream>>>(Wq, Wk, Wv, Wt);
    qkv_kernel<<<NROWS / 32, 256, 0, stream>>>(x, Wt, temp_emb, sp_emb, Qb, Kb, Vb);
    attn_kernel<<<(HH / ATY) * (WWD / ATX), 384, 0, stream>>>(Qb, Kb, Vb, sp_emb, Qb);
    out_proj_kernel<<<NROWS / 32, 256, 0, stream>>>(Qb, Wo, out);
}

// Round 4
// 199.557 us; speedup vs baseline: 1.1490x; 1.1490x over previous
//
#include <hip/hip_runtime.h>
#include <hip/hip_bf16.h>
#include <math.h>

#define TT 3
#define HH 96
#define WWD 96
#define CCH 128
#define NROWS (TT*HH*WWD)   // 27648

typedef __attribute__((ext_vector_type(8))) short short8;
typedef __attribute__((ext_vector_type(4))) float float4v;

__device__ __forceinline__ float bfu(unsigned short u){ union{unsigned u;float f;}c; c.u=((unsigned)u)<<16; return c.f; }
__device__ __forceinline__ unsigned short f2bf(float f){ __hip_bfloat16 h=__float2bfloat16(f); return *(unsigned short*)&h; }

// ---------------- Kernel 0: weight prep ----------------
// Wt[384][128] bf16 = [Wq;Wk;Wv]^T (k-contig). Wo1/Wo2 = double-bf16 of Wo^T.
// spb[32][128] bf16 of sp_emb (rows 25..31 zeroed).
__global__ void prep_kernel(const float* __restrict__ Wq, const float* __restrict__ Wk,
                            const float* __restrict__ Wv, const float* __restrict__ Wo,
                            const float* __restrict__ sp_emb,
                            unsigned short* __restrict__ Wt, unsigned short* __restrict__ Wo1,
                            unsigned short* __restrict__ Wo2, unsigned short* __restrict__ spb) {
    int gid = blockIdx.x * 256 + threadIdx.x;
    int gsz = gridDim.x * 256;
    for (int e = gid; e < 3 * 16384; e += gsz) {
        int m = e >> 14, r = e & 16383, k = r >> 7, n = r & 127;
        const float* src = (m == 0) ? Wq : (m == 1) ? Wk : Wv;
        Wt[(size_t)(m * 128 + n) * 128 + k] = f2bf(src[k * 128 + n]);
    }
    for (int e = gid; e < 16384; e += gsz) {
        int k = e >> 7, n = e & 127;
        float wv = Wo[k * 128 + n];
        unsigned short w1 = f2bf(wv);
        Wo1[(size_t)n * 128 + k] = w1;
        Wo2[(size_t)n * 128 + k] = f2bf(wv - bfu(w1));
    }
    for (int e = gid; e < 32 * 128; e += gsz) {
        int p = e >> 7, k = e & 127;
        spb[e] = (p < 25) ? f2bf(sp_emb[p * 128 + k]) : (unsigned short)0;
    }
}

// ---------------- Kernel 1: QKV projection, bf16 MFMA (swapped operands) ----------------
// M = 384 concat cols, N = 32 queries. C: col(l16)=query, row(quad*4+reg)=col -> ushort4 stores.
__launch_bounds__(256)
__global__ void qkv_kernel(const float* __restrict__ x,
                           const unsigned short* __restrict__ Wt,
                           const float* __restrict__ temp_emb,
                           const float* __restrict__ sp_emb,
                           unsigned short* __restrict__ Qb,
                           unsigned short* __restrict__ Kb,
                           unsigned short* __restrict__ Vb) {
    __shared__ unsigned short xs[32 * 136];
    const int tid = threadIdx.x;
    const int q0 = blockIdx.x * 32;
    for (int e = tid; e < 1024; e += 256) {
        int row = e >> 5, col = (e & 31) * 4;
        float4 v = *(const float4*)(x + (size_t)(q0 + row) * CCH + col);
        ushort4 u; u.x = f2bf(v.x); u.y = f2bf(v.y); u.z = f2bf(v.z); u.w = f2bf(v.w);
        *(ushort4*)&xs[row * 136 + col] = u;
    }
    __syncthreads();
    const int w = tid >> 6, lane = tid & 63, quad = lane >> 4, l16 = lane & 15;
    float4v acc[6][2];
#pragma unroll
    for (int mt = 0; mt < 6; ++mt) { acc[mt][0] = (float4v){0,0,0,0}; acc[mt][1] = (float4v){0,0,0,0}; }
#pragma unroll
    for (int ks = 0; ks < 4; ++ks) {
        short8 b0 = *(const short8*)&xs[l16 * 136 + ks * 32 + quad * 8];
        short8 b1 = *(const short8*)&xs[(16 + l16) * 136 + ks * 32 + quad * 8];
#pragma unroll
        for (int mt = 0; mt < 6; ++mt) {
            short8 a = *(const short8*)(Wt + (size_t)(w * 96 + mt * 16 + l16) * CCH + ks * 32 + quad * 8);
            acc[mt][0] = __builtin_amdgcn_mfma_f32_16x16x32_bf16(a, b0, acc[mt][0], 0, 0, 0);
            acc[mt][1] = __builtin_amdgcn_mfma_f32_16x16x32_bf16(a, b1, acc[mt][1], 0, 0, 0);
        }
    }
#pragma unroll
    for (int nt = 0; nt < 2; ++nt) {
        int q = q0 + nt * 16 + l16;
        int t = q / (HH * WWD); int rem = q - t * (HH * WWD);
        int yy = rem / WWD, xx = rem - (rem / WWD) * WWD;
        int qidx = (yy - min(max(yy, 2), 93) + 2) * 5 + (xx - min(max(xx, 2), 93) + 2);
#pragma unroll
        for (int mt = 0; mt < 6; ++mt) {
            int colc = w * 96 + mt * 16 + quad * 4;
            int mat = colc >> 7, colb = colc & 127;
            float4v a = acc[mt][nt];
            ushort4 u;
            if (mat == 0) {
                float4 te = *(const float4*)(temp_emb + t * CCH + colb);
                float4 se = *(const float4*)(sp_emb + qidx * CCH + colb);
                u.x = f2bf((a[0] + te.x + se.x) * 0.25f);
                u.y = f2bf((a[1] + te.y + se.y) * 0.25f);
                u.z = f2bf((a[2] + te.z + se.z) * 0.25f);
                u.w = f2bf((a[3] + te.w + se.w) * 0.25f);
                *(ushort4*)(Qb + (size_t)q * CCH + colb) = u;
            } else if (mat == 1) {
                float4 te = *(const float4*)(temp_emb + t * CCH + colb);
                u.x = f2bf(a[0] + te.x); u.y = f2bf(a[1] + te.y);
                u.z = f2bf(a[2] + te.z); u.w = f2bf(a[3] + te.w);
                *(ushort4*)(Kb + (size_t)q * CCH + colb) = u;
            } else {
                u.x = f2bf(a[0]); u.y = f2bf(a[1]); u.z = f2bf(a[2]); u.w = f2bf(a[3]);
                *(ushort4*)(Vb + (size_t)q * CCH + colb) = u;
            }
        }
    }
}

// ---------------- Kernel 2: MFMA flash-style local attention ----------------
// Block = 4x4 query tile, 256 thr = 4 waves; wave owns heads {w, w+4} x 3 tq.
// S = Q.K^T via mfma (K=16 zero-padded to 32); mask+qsp per element; P via LDS
// relayout; PV via mfma with V staged transposed. Output written over Qb.
__launch_bounds__(256, 2)
__global__ void attn_kernel(unsigned short* Qb,
                            const unsigned short* __restrict__ Kb,
                            const unsigned short* __restrict__ Vb,
                            const unsigned short* __restrict__ spb) {
    __shared__ unsigned short Qs[3 * 16 * 136];     // 6528 sh
    __shared__ unsigned short Ks[64 * 136];         // 8704 sh
    __shared__ unsigned short Vst[128 * 72];        // 9216 sh (transposed: [d][slot])
    __shared__ unsigned short Ps[4][16 * 72];       // per-wave P buffer
    __shared__ unsigned short qspt[4][6][16 * 28];  // per-wave qsp tables (bf16)

    const int tid = threadIdx.x;
    const int w = tid >> 6, lane = tid & 63, quad = lane >> 4, l16 = lane & 15;
    const int bx = blockIdx.x % (WWD / 4), by = blockIdx.x / (WWD / 4);
    const int x0 = bx * 4, y0 = by * 4;
    const int xlo = min(min(max(x0, 2), 93) - 2, WWD - 8);
    const int ylo = min(min(max(y0, 2), 93) - 2, HH - 8);

    // stage Q tile (3 tq x 16 q x 128d bf16)
    for (int e = tid; e < 768; e += 256) {
        int c = e & 15, q = (e >> 4) & 15, tq = e >> 8;
        int qr = tq * (HH * WWD) + (y0 + (q >> 2)) * WWD + x0 + (q & 3);
        *(uint4*)&Qs[tq * 2176 + q * 136 + c * 8] = *(const uint4*)(Qb + (size_t)qr * CCH + c * 8);
    }
    __syncthreads();

    const short8 zero8 = {0, 0, 0, 0, 0, 0, 0, 0};
    short8 aq[2][3];
#pragma unroll
    for (int hh = 0; hh < 2; ++hh) {
        int h16 = (w + hh * 4) * 16;
#pragma unroll
        for (int tq = 0; tq < 3; ++tq)
            aq[hh][tq] = (quad < 2) ? *(const short8*)&Qs[tq * 2176 + l16 * 136 + h16 + quad * 8] : zero8;
    }

    // qsp tables via MFMA: qsp[q][p] = (0.25Q).sp_p
#pragma unroll
    for (int hh = 0; hh < 2; ++hh) {
        int h16 = (w + hh * 4) * 16;
#pragma unroll
        for (int tq = 0; tq < 3; ++tq) {
#pragma unroll
            for (int n2 = 0; n2 < 2; ++n2) {
                short8 bs = (quad < 2) ? *(const short8*)(spb + (size_t)(n2 * 16 + l16) * CCH + h16 + quad * 8) : zero8;
                float4v c = {0, 0, 0, 0};
                c = __builtin_amdgcn_mfma_f32_16x16x32_bf16(aq[hh][tq], bs, c, 0, 0, 0);
                int p = n2 * 16 + l16;
                if (p < 25) {
                    unsigned short* qt = &qspt[w][hh * 3 + tq][0];
#pragma unroll
                    for (int reg = 0; reg < 4; ++reg)
                        qt[(quad * 4 + reg) * 28 + p] = f2bf(c[reg]);
                }
            }
        }
    }
    __builtin_amdgcn_wave_barrier();   // in-wave LDS RAW fence (qspt)

    // per-lane query geometry: qy = quad, qx = reg
    const int yy = y0 + quad;
    const int yc = min(max(yy, 2), 93);
    const int ay = ylo + 2 - yc;
    int ax[4];
#pragma unroll
    for (int reg = 0; reg < 4; ++reg) {
        int xx = x0 + reg;
        ax[reg] = xlo + 2 - min(max(xx, 2), 93);
    }

    float mrow[6][4], lrow[6][4];
    float4v Oacc[6];
#pragma unroll
    for (int i = 0; i < 6; ++i) {
        Oacc[i] = (float4v){0, 0, 0, 0};
#pragma unroll
        for (int reg = 0; reg < 4; ++reg) { mrow[i][reg] = -1e30f; lrow[i][reg] = 0.f; }
    }

    for (int t = 0; t < TT; ++t) {
        __syncthreads();
        // stage K (key-major) and V (transposed) halos, 64 slots x 128d bf16
        for (int e = tid; e < 1024; e += 256) {
            int c = e & 15, slot = e >> 4;
            int gy = ylo + (slot >> 3), gx = xlo + (slot & 7);
            size_t g = ((size_t)(t * HH + gy) * WWD + gx) * CCH + c * 8;
            *(uint4*)&Ks[slot * 136 + c * 8] = *(const uint4*)(Kb + g);
            uint4 vv = *(const uint4*)(Vb + g);
            const unsigned short* vs = (const unsigned short*)&vv;
#pragma unroll
            for (int j = 0; j < 8; ++j)
                Vst[(c * 8 + j) * 72 + slot] = vs[j];
        }
        __syncthreads();

#pragma unroll
        for (int hh = 0; hh < 2; ++hh) {
            int h16 = (w + hh * 4) * 16;
            short8 bk[4];
#pragma unroll
            for (int n = 0; n < 4; ++n)
                bk[n] = (quad < 2) ? *(const short8*)&Ks[(n * 16 + l16) * 136 + h16 + quad * 8] : zero8;
            short8 bv0 = *(const short8*)&Vst[(h16 + l16) * 72 + quad * 8];
            short8 bv1 = *(const short8*)&Vst[(h16 + l16) * 72 + 32 + quad * 8];
#pragma unroll
            for (int tq = 0; tq < 3; ++tq) {
                int idx = hh * 3 + tq;
                float4v S[4];
#pragma unroll
                for (int n = 0; n < 4; ++n) {
                    float4v z = {0, 0, 0, 0};
                    S[n] = __builtin_amdgcn_mfma_f32_16x16x32_bf16(aq[hh][tq], bk[n], z, 0, 0, 0);
                }
                const unsigned short* qt = &qspt[w][idx][0];
                float sv[4][4];
                float fm[4] = {-1e30f, -1e30f, -1e30f, -1e30f};
#pragma unroll
                for (int n = 0; n < 4; ++n) {
                    int dy = 2 * n + (l16 >> 3) + ay;
                    int kx = l16 & 7;
                    bool vy = (unsigned)dy < 5u;
#pragma unroll
                    for (int reg = 0; reg < 4; ++reg) {
                        int dx = kx + ax[reg];
                        bool v = vy && ((unsigned)dx < 5u);
                        int p = v ? (dy * 5 + dx) : 0;
                        float qa = bfu(qt[(quad * 4 + reg) * 28 + p]);
                        sv[n][reg] = v ? (S[n][reg] + qa) : -1e30f;
                        fm[reg] = fmaxf(fm[reg], sv[n][reg]);
                    }
                }
#pragma unroll
                for (int reg = 0; reg < 4; ++reg) {
#pragma unroll
                    for (int d = 1; d < 16; d <<= 1)
                        fm[reg] = fmaxf(fm[reg], __shfl_xor(fm[reg], d));
                }
                float corr[4], rs[4];
#pragma unroll
                for (int reg = 0; reg < 4; ++reg) {
                    float nm = fmaxf(mrow[idx][reg], fm[reg]);
                    corr[reg] = __expf(mrow[idx][reg] - nm);
                    mrow[idx][reg] = nm;
                    rs[reg] = 0.f;
                }
                __builtin_amdgcn_wave_barrier();  // prev PV reads done before overwrite
#pragma unroll
                for (int n = 0; n < 4; ++n)
#pragma unroll
                    for (int reg = 0; reg < 4; ++reg) {
                        float wv = __expf(sv[n][reg] - mrow[idx][reg]);
                        rs[reg] += wv;
                        Ps[w][(quad * 4 + reg) * 72 + n * 16 + l16] = f2bf(wv);
                    }
#pragma unroll
                for (int reg = 0; reg < 4; ++reg) {
#pragma unroll
                    for (int d = 1; d < 16; d <<= 1)
                        rs[reg] += __shfl_xor(rs[reg], d);
                    lrow[idx][reg] = lrow[idx][reg] * corr[reg] + rs[reg];
                    Oacc[idx][reg] *= corr[reg];
                }
                __builtin_amdgcn_wave_barrier();  // P writes before A-frag reads
                short8 ap0 = *(const short8*)&Ps[w][l16 * 72 + quad * 8];
                short8 ap1 = *(const short8*)&Ps[w][l16 * 72 + 32 + quad * 8];
                Oacc[idx] = __builtin_amdgcn_mfma_f32_16x16x32_bf16(ap0, bv0, Oacc[idx], 0, 0, 0);
                Oacc[idx] = __builtin_amdgcn_mfma_f32_16x16x32_bf16(ap1, bv1, Oacc[idx], 0, 0, 0);
            }
        }
    }
    // epilogue: O[q][d] C-layout -> Qb (in place); col=l16=d, row=quad*4+reg=q
#pragma unroll
    for (int hh = 0; hh < 2; ++hh) {
        int h16 = (w + hh * 4) * 16;
#pragma unroll
        for (int tq = 0; tq < 3; ++tq) {
            int idx = hh * 3 + tq;
#pragma unroll
            for (int reg = 0; reg < 4; ++reg) {
                int qr = tq * (HH * WWD) + (y0 + quad) * WWD + x0 + reg;
                Qb[(size_t)qr * CCH + h16 + l16] = f2bf(Oacc[idx][reg] / lrow[idx][reg]);
            }
        }
    }
}

// ---------------- Kernel 3: output projection, MFMA double-bf16 Wo + transpose scatter ----------------
__launch_bounds__(256)
__global__ void out_proj_kernel(const unsigned short* __restrict__ A,
                                const unsigned short* __restrict__ Wo1,
                                const unsigned short* __restrict__ Wo2,
                                float* __restrict__ out) {
    __shared__ unsigned short as[32 * 136];
    const int tid = threadIdx.x;
    const int q0 = blockIdx.x * 32;
    for (int e = tid; e < 512; e += 256) {
        int row = e >> 4, c = e & 15;
        *(uint4*)&as[row * 136 + c * 8] = *(const uint4*)(A + (size_t)(q0 + row) * CCH + c * 8);
    }
    __syncthreads();
    const int w = tid >> 6, lane = tid & 63, quad = lane >> 4, l16 = lane & 15;
    float4v acc[2][2];
#pragma unroll
    for (int mt = 0; mt < 2; ++mt) { acc[mt][0] = (float4v){0,0,0,0}; acc[mt][1] = (float4v){0,0,0,0}; }
#pragma unroll
    for (int ks = 0; ks < 4; ++ks) {
        short8 b0 = *(const short8*)&as[l16 * 136 + ks * 32 + quad * 8];
        short8 b1 = *(const short8*)&as[(16 + l16) * 136 + ks * 32 + quad * 8];
#pragma unroll
        for (int mt = 0; mt < 2; ++mt) {
            size_t wo = (size_t)(w * 32 + mt * 16 + l16) * CCH + ks * 32 + quad * 8;
            short8 a1 = *(const short8*)(Wo1 + wo);
            short8 a2 = *(const short8*)(Wo2 + wo);
            acc[mt][0] = __builtin_amdgcn_mfma_f32_16x16x32_bf16(a1, b0, acc[mt][0], 0, 0, 0);
            acc[mt][0] = __builtin_amdgcn_mfma_f32_16x16x32_bf16(a2, b0, acc[mt][0], 0, 0, 0);
            acc[mt][1] = __builtin_amdgcn_mfma_f32_16x16x32_bf16(a1, b1, acc[mt][1], 0, 0, 0);
            acc[mt][1] = __builtin_amdgcn_mfma_f32_16x16x32_bf16(a2, b1, acc[mt][1], 0, 0, 0);
        }
    }
#pragma unroll
    for (int nt = 0; nt < 2; ++nt) {
        int q = q0 + nt * 16 + l16;
        int t = q / (HH * WWD); int rem = q - t * (HH * WWD);
        int yy = rem / WWD, xx = rem - (rem / WWD) * WWD;
        size_t ob = ((size_t)(yy * WWD + xx) * TT + t) * CCH;
#pragma unroll
        for (int mt = 0; mt < 2; ++mt) {
            float4 o;
            o.x = acc[mt][nt][0]; o.y = acc[mt][nt][1];
            o.z = acc[mt][nt][2]; o.w = acc[mt][nt][3];
            *(float4*)(out + ob + w * 32 + mt * 16 + quad * 4) = o;
        }
    }
}

extern "C" void kernel_launch(void* const* d_in, const int* in_sizes, int n_in,
                              void* d_out, int out_size, void* d_ws, size_t ws_size,
                              hipStream_t stream) {
    const float* x        = (const float*)d_in[0];
    const float* Wq       = (const float*)d_in[1];
    const float* Wk       = (const float*)d_in[2];
    const float* Wv       = (const float*)d_in[3];
    const float* Wo       = (const float*)d_in[4];
    const float* temp_emb = (const float*)d_in[5];
    const float* sp_emb   = (const float*)d_in[6];
    float* out = (float*)d_out;

    const size_t nb = (size_t)NROWS * CCH * 2;   // bytes per bf16 buffer
    unsigned short* Qb  = (unsigned short*)d_ws;
    unsigned short* Kb  = (unsigned short*)((char*)d_ws + nb);
    unsigned short* Vb  = (unsigned short*)((char*)d_ws + 2 * nb);
    unsigned short* Wt  = (unsigned short*)((char*)d_ws + 3 * nb);
    unsigned short* Wo1 = Wt + 384 * 128;
    unsigned short* Wo2 = Wo1 + 128 * 128;
    unsigned short* spb = Wo2 + 128 * 128;

    prep_kernel<<<96, 256, 0, stream>>>(Wq, Wk, Wv, Wo, sp_emb, Wt, Wo1, Wo2, spb);
    qkv_kernel<<<NROWS / 32, 256, 0, stream>>>(x, Wt, temp_emb, sp_emb, Qb, Kb, Vb);
    attn_kernel<<<(HH / 4) * (WWD / 4), 256, 0, stream>>>(Qb, Kb, Vb, spb);
    out_proj_kernel<<<NROWS / 32, 256, 0, stream>>>(Qb, Wo1, Wo2, out);
}